// Round 6
// baseline (39.081 us; speedup 1.0000x reference)
//
#include <hip/hip_runtime.h>
#include <math.h>

static constexpr int B_ = 32;
static constexpr int T_ = 512;
static constexpr int D_ = 1024;
static constexpr int NT_ = 32;            // t-chunks per sample
static constexpr int TCHUNK_ = T_ / NT_;  // 16 rows per chunk (compile-time)
static constexpr int GRID1_ = 1024;       // pass-1 blocks (4/CU)
static constexpr float EPS_ = 1e-12f;

__device__ __forceinline__ float sl1f(float x) {
    float a = fabsf(x);
    return a < 1.0f ? 0.5f * x * x : a - 0.5f;
}

// Full 256-thread block reduce; returns total broadcast to all threads.
__device__ __forceinline__ float blockReduce256(float v, float* lds) {
#pragma unroll
    for (int o = 32; o > 0; o >>= 1) v += __shfl_down(v, o, 64);
    int wid = threadIdx.x >> 6, lane = threadIdx.x & 63;
    if (lane == 0) lds[wid] = v;
    __syncthreads();
    float tot = lds[0] + lds[1] + lds[2] + lds[3];
    __syncthreads();
    return tot;
}

// Pass 1: identical to round 5 (flat balanced chunk list). PROBE: launched twice
// this round; it is idempotent (same writes both times), so output is unchanged
// and dur_us(new) - dur_us(round5) = pass1 replay duration.
__global__ __launch_bounds__(256, 4) void pass1_kernel(
    const float* __restrict__ preds, const float* __restrict__ wtarg,
    const int* __restrict__ lens,
    float* __restrict__ wsPred, float* __restrict__ wsTarg, float* __restrict__ wsSl1)
{
    __shared__ float lds[4];
    __shared__ int sPrefix[B_ + 1];   // exclusive prefix of ceil(len/16); [B_]=total
    __shared__ int sLen[B_];

    const int tid = threadIdx.x;
    if (tid < 64) {
        int len_t = (tid < B_) ? lens[tid] : 0;
        int nc = (len_t + TCHUNK_ - 1) / TCHUNK_;
        int incl = nc;
#pragma unroll
        for (int o = 1; o < 64; o <<= 1) {
            int u = __shfl_up(incl, o, 64);
            if (tid >= o) incl += u;
        }
        if (tid < B_) { sPrefix[tid] = incl - nc; sLen[tid] = len_t; }
        if (tid == B_ - 1) sPrefix[B_] = incl;
    }
    __syncthreads();
    const int total = sPrefix[B_];

    for (int fi = blockIdx.x; fi < total; fi += GRID1_) {
        int lo = 0, hi = B_;
        while (hi - lo > 1) {
            int mid = (lo + hi) >> 1;
            if (sPrefix[mid] <= fi) lo = mid; else hi = mid;
        }
        const int b = lo;
        const int c = fi - sPrefix[lo];
        const int len = sLen[b];
        const int t0 = c * TCHUNK_;
        const int nrows = min(TCHUNK_, len - t0);

        const float4* pp = reinterpret_cast<const float4*>(preds)
                           + (size_t)(b * T_ + t0) * (D_ / 4) + tid;
        const float4* pw = reinterpret_cast<const float4*>(wtarg)
                           + (size_t)(b * T_ + t0) * (D_ / 4) + tid;

        float4 ps = make_float4(0.f, 0.f, 0.f, 0.f);
        float4 ts = make_float4(0.f, 0.f, 0.f, 0.f);
        float s = 0.f;

        if (nrows == TCHUNK_) {
#pragma unroll
            for (int tt = 0; tt < TCHUNK_; tt += 8) {
                float4 p[8], w[8];
#pragma unroll
                for (int j = 0; j < 8; ++j) p[j] = pp[(size_t)(tt + j) * (D_ / 4)];
#pragma unroll
                for (int j = 0; j < 8; ++j) w[j] = pw[(size_t)(tt + j) * (D_ / 4)];
#pragma unroll
                for (int j = 0; j < 8; ++j) {
                    ps.x += p[j].x; ps.y += p[j].y; ps.z += p[j].z; ps.w += p[j].w;
                    ts.x += w[j].x; ts.y += w[j].y; ts.z += w[j].z; ts.w += w[j].w;
                    s += sl1f(p[j].x - w[j].x) + sl1f(p[j].y - w[j].y)
                       + sl1f(p[j].z - w[j].z) + sl1f(p[j].w - w[j].w);
                }
            }
        } else {
            for (int t = 0; t < nrows; ++t) {
                float4 p = pp[(size_t)t * (D_ / 4)];
                float4 w = pw[(size_t)t * (D_ / 4)];
                ps.x += p.x; ps.y += p.y; ps.z += p.z; ps.w += p.w;
                ts.x += w.x; ts.y += w.y; ts.z += w.z; ts.w += w.w;
                s += sl1f(p.x - w.x) + sl1f(p.y - w.y) + sl1f(p.z - w.z) + sl1f(p.w - w.w);
            }
        }

        const size_t off = ((size_t)b * NT_ + c) * (D_ / 4) + tid;
        reinterpret_cast<float4*>(wsPred)[off] = ps;
        reinterpret_cast<float4*>(wsTarg)[off] = ts;

        float tot = blockReduce256(s, lds);
        if (tid == 0) wsSl1[b * NT_ + c] = tot;
    }
}

// Pass 2: unchanged from round 5.
__global__ __launch_bounds__(256) void pass2_kernel(
    const float* __restrict__ img, const int* __restrict__ lens,
    const float* __restrict__ wsPred, const float* __restrict__ wsTarg,
    const float* __restrict__ wsSl1, float* __restrict__ wsP)
{
    __shared__ float4 lA[8][32];
    __shared__ float4 lB[8][32];
    __shared__ float lred[4];

    const int g = blockIdx.x, b = blockIdx.y;
    const int tid = threadIdx.x;
    const int c8 = tid >> 5, j = tid & 31;
    const int len = lens[b];
    const float flen = (float)len;
    const int ntmax = (len + TCHUNK_ - 1) / TCHUNK_;

    const float4* img4 = reinterpret_cast<const float4*>(img);
    float4 im = img4[(size_t)b * (D_ / 4) + tid];
    float ss = im.x * im.x + im.y * im.y + im.z * im.z + im.w * im.w;
    float sumsq = blockReduce256(ss, lred);
    float inv_norm = 1.0f / fmaxf(sqrtf(sumsq), EPS_);

    float4 ap = make_float4(0.f, 0.f, 0.f, 0.f);
    float4 at = make_float4(0.f, 0.f, 0.f, 0.f);
#pragma unroll
    for (int k = 0; k < NT_ / 8; ++k) {
        int nt = c8 + k * 8;
        if (nt < ntmax) {
            size_t off = ((size_t)b * NT_ + nt) * (D_ / 4) + (size_t)g * 32 + j;
            float4 p = reinterpret_cast<const float4*>(wsPred)[off];
            float4 w = reinterpret_cast<const float4*>(wsTarg)[off];
            ap.x += p.x; ap.y += p.y; ap.z += p.z; ap.w += p.w;
            at.x += w.x; at.y += w.y; at.z += w.z; at.w += w.w;
        }
    }
    lA[c8][j] = ap;
    lB[c8][j] = at;
    __syncthreads();

    float part = 0.f;
    if (tid < 32) {
        float4 ps = make_float4(0.f, 0.f, 0.f, 0.f);
        float4 ts = make_float4(0.f, 0.f, 0.f, 0.f);
#pragma unroll
        for (int k = 0; k < 8; ++k) {
            float4 p = lA[k][tid], w = lB[k][tid];
            ps.x += p.x; ps.y += p.y; ps.z += p.z; ps.w += p.w;
            ts.x += w.x; ts.y += w.y; ts.z += w.z; ts.w += w.w;
        }
        const float pmx = ps.x / flen, pmy = ps.y / flen, pmz = ps.z / flen, pmw = ps.w / flen;
        const float tmx = ts.x / flen, tmy = ts.y / flen, tmz = ts.z / flen, tmw = ts.w / flen;
        float4 iv = img4[(size_t)b * (D_ / 4) + g * 32 + tid];
        part  = sl1f(pmx - tmx) + sl1f(pmy - tmy) + sl1f(pmz - tmz) + sl1f(pmw - tmw);
        part += sl1f(pmx - iv.x * inv_norm) + sl1f(pmy - iv.y * inv_norm)
              + sl1f(pmz - iv.z * inv_norm) + sl1f(pmw - iv.w * inv_norm);
    }
#pragma unroll
    for (int o = 16; o > 0; o >>= 1) part += __shfl_down(part, o, 64);

    if (tid == 0) {
        float wsum = 0.f;
#pragma unroll
        for (int k = 0; k < NT_ / 8; ++k) {
            int nt = g * (NT_ / 8) + k;
            if (nt < ntmax) wsum += wsSl1[b * NT_ + nt];
        }
        wsP[b * 8 + g] = part / (float)D_ + wsum / (flen * (float)D_);
    }
}

// Pass 3: unchanged from round 5.
__global__ __launch_bounds__(256) void pass3_kernel(const float* __restrict__ wsP,
                                                    float* __restrict__ out)
{
    __shared__ float lred[4];
    float v = wsP[threadIdx.x];
    float tot = blockReduce256(v, lred);
    if (threadIdx.x == 0) out[0] = tot / (float)B_;
}

extern "C" void kernel_launch(void* const* d_in, const int* in_sizes, int n_in,
                              void* d_out, int out_size, void* d_ws, size_t ws_size,
                              hipStream_t stream) {
    const float* wtarg = (const float*)d_in[0];   // word_targets [B,T,D]
    const float* img   = (const float*)d_in[1];   // image_targets [B,D]
    const float* preds = (const float*)d_in[2];   // preds [B,T,D]
    const int*   lens  = (const int*)d_in[3];     // decode_lengths [B]
    float* out = (float*)d_out;

    float* wsPred = (float*)d_ws;                          // B*NT*D floats (4 MB)
    float* wsTarg = wsPred + (size_t)B_ * NT_ * D_;        // 4 MB
    float* wsSl1  = wsTarg + (size_t)B_ * NT_ * D_;        // B*NT
    float* wsP    = wsSl1 + (size_t)B_ * NT_;              // 256 floats

    // PROBE: pass1 launched twice (idempotent). dur_us - round5_dur == pass1 dur.
    pass1_kernel<<<GRID1_, 256, 0, stream>>>(preds, wtarg, lens, wsPred, wsTarg, wsSl1);
    pass1_kernel<<<GRID1_, 256, 0, stream>>>(preds, wtarg, lens, wsPred, wsTarg, wsSl1);
    pass2_kernel<<<dim3(8, B_), 256, 0, stream>>>(img, lens, wsPred, wsTarg, wsSl1, wsP);
    pass3_kernel<<<1, 256, 0, stream>>>(wsP, out);
}

// Round 7
// 24.663 us; speedup vs baseline: 1.5846x; 1.5846x over previous
//
#include <hip/hip_runtime.h>
#include <math.h>

static constexpr int B_ = 32;
static constexpr int T_ = 512;
static constexpr int D_ = 1024;
static constexpr int NT_ = 32;            // t-chunks per sample
static constexpr int TCHUNK_ = T_ / NT_;  // 16 rows per chunk (compile-time)
static constexpr int GRID1_ = 1024;       // pass-1 blocks (4/CU)
static constexpr float EPS_ = 1e-12f;

__device__ __forceinline__ float sl1f(float x) {
    float a = fabsf(x);
    return a < 1.0f ? 0.5f * x * x : a - 0.5f;
}

// Full 256-thread block reduce; returns total broadcast to all threads.
__device__ __forceinline__ float blockReduce256(float v, float* lds) {
#pragma unroll
    for (int o = 32; o > 0; o >>= 1) v += __shfl_down(v, o, 64);
    int wid = threadIdx.x >> 6, lane = threadIdx.x & 63;
    if (lane == 0) lds[wid] = v;
    __syncthreads();
    float tot = lds[0] + lds[1] + lds[2] + lds[3];
    __syncthreads();
    return tot;
}

// Pass 1: flat balanced chunk list (round-5 structure, measured 13.2 us).
// Also zeroes out[0] each call (kernel boundary orders this before pass 2's
// atomic accumulation; harness does not re-poison d_out between replays).
__global__ __launch_bounds__(256, 4) void pass1_kernel(
    const float* __restrict__ preds, const float* __restrict__ wtarg,
    const int* __restrict__ lens,
    float* __restrict__ wsPred, float* __restrict__ wsTarg, float* __restrict__ wsSl1,
    float* __restrict__ out)
{
    __shared__ float lds[4];
    __shared__ int sPrefix[B_ + 1];   // exclusive prefix of ceil(len/16); [B_]=total
    __shared__ int sLen[B_];

    const int tid = threadIdx.x;
    if (blockIdx.x == 0 && tid == 0) out[0] = 0.f;

    if (tid < 64) {
        int len_t = (tid < B_) ? lens[tid] : 0;
        int nc = (len_t + TCHUNK_ - 1) / TCHUNK_;
        int incl = nc;
#pragma unroll
        for (int o = 1; o < 64; o <<= 1) {
            int u = __shfl_up(incl, o, 64);
            if (tid >= o) incl += u;
        }
        if (tid < B_) { sPrefix[tid] = incl - nc; sLen[tid] = len_t; }
        if (tid == B_ - 1) sPrefix[B_] = incl;
    }
    __syncthreads();
    const int total = sPrefix[B_];

    for (int fi = blockIdx.x; fi < total; fi += GRID1_) {
        // binary search: largest b with sPrefix[b] <= fi (uniform across block)
        int lo = 0, hi = B_;
        while (hi - lo > 1) {
            int mid = (lo + hi) >> 1;
            if (sPrefix[mid] <= fi) lo = mid; else hi = mid;
        }
        const int b = lo;
        const int c = fi - sPrefix[lo];
        const int len = sLen[b];
        const int t0 = c * TCHUNK_;
        const int nrows = min(TCHUNK_, len - t0);

        const float4* pp = reinterpret_cast<const float4*>(preds)
                           + (size_t)(b * T_ + t0) * (D_ / 4) + tid;
        const float4* pw = reinterpret_cast<const float4*>(wtarg)
                           + (size_t)(b * T_ + t0) * (D_ / 4) + tid;

        float4 ps = make_float4(0.f, 0.f, 0.f, 0.f);
        float4 ts = make_float4(0.f, 0.f, 0.f, 0.f);
        float s = 0.f;

        if (nrows == TCHUNK_) {
#pragma unroll
            for (int tt = 0; tt < TCHUNK_; tt += 8) {
                float4 p[8], w[8];
#pragma unroll
                for (int j = 0; j < 8; ++j) p[j] = pp[(size_t)(tt + j) * (D_ / 4)];
#pragma unroll
                for (int j = 0; j < 8; ++j) w[j] = pw[(size_t)(tt + j) * (D_ / 4)];
#pragma unroll
                for (int j = 0; j < 8; ++j) {
                    ps.x += p[j].x; ps.y += p[j].y; ps.z += p[j].z; ps.w += p[j].w;
                    ts.x += w[j].x; ts.y += w[j].y; ts.z += w[j].z; ts.w += w[j].w;
                    s += sl1f(p[j].x - w[j].x) + sl1f(p[j].y - w[j].y)
                       + sl1f(p[j].z - w[j].z) + sl1f(p[j].w - w[j].w);
                }
            }
        } else {
            for (int t = 0; t < nrows; ++t) {
                float4 p = pp[(size_t)t * (D_ / 4)];
                float4 w = pw[(size_t)t * (D_ / 4)];
                ps.x += p.x; ps.y += p.y; ps.z += p.z; ps.w += p.w;
                ts.x += w.x; ts.y += w.y; ts.z += w.z; ts.w += w.w;
                s += sl1f(p.x - w.x) + sl1f(p.y - w.y) + sl1f(p.z - w.z) + sl1f(p.w - w.w);
            }
        }

        const size_t off = ((size_t)b * NT_ + c) * (D_ / 4) + tid;
        reinterpret_cast<float4*>(wsPred)[off] = ps;
        reinterpret_cast<float4*>(wsTarg)[off] = ts;

        float tot = blockReduce256(s, lds);
        if (tid == 0) wsSl1[b * NT_ + c] = tot;
    }
}

// Pass 2: grid (8, B_). Same combine as round 5, but the per-(g,b) partial loss
// is accumulated straight into out[0] via device-scope atomicAdd (cross-XCD
// coherent; NO threadfence). Replaces pass 3 entirely.
__global__ __launch_bounds__(256) void pass2_kernel(
    const float* __restrict__ img, const int* __restrict__ lens,
    const float* __restrict__ wsPred, const float* __restrict__ wsTarg,
    const float* __restrict__ wsSl1, float* __restrict__ out)
{
    __shared__ float4 lA[8][32];
    __shared__ float4 lB[8][32];
    __shared__ float lred[4];

    const int g = blockIdx.x, b = blockIdx.y;
    const int tid = threadIdx.x;
    const int c8 = tid >> 5, j = tid & 31;
    const int len = lens[b];
    const float flen = (float)len;
    const int ntmax = (len + TCHUNK_ - 1) / TCHUNK_;   // chunks actually written

    // image norm over the full row (all 256 threads)
    const float4* img4 = reinterpret_cast<const float4*>(img);
    float4 im = img4[(size_t)b * (D_ / 4) + tid];
    float ss = im.x * im.x + im.y * im.y + im.z * im.z + im.w * im.w;
    float sumsq = blockReduce256(ss, lred);
    float inv_norm = 1.0f / fmaxf(sqrtf(sumsq), EPS_);

    // partial chunk reduction (skip never-written chunks: ws is poisoned)
    float4 ap = make_float4(0.f, 0.f, 0.f, 0.f);
    float4 at = make_float4(0.f, 0.f, 0.f, 0.f);
#pragma unroll
    for (int k = 0; k < NT_ / 8; ++k) {
        int nt = c8 + k * 8;
        if (nt < ntmax) {
            size_t off = ((size_t)b * NT_ + nt) * (D_ / 4) + (size_t)g * 32 + j;
            float4 p = reinterpret_cast<const float4*>(wsPred)[off];
            float4 w = reinterpret_cast<const float4*>(wsTarg)[off];
            ap.x += p.x; ap.y += p.y; ap.z += p.z; ap.w += p.w;
            at.x += w.x; at.y += w.y; at.z += w.z; at.w += w.w;
        }
    }
    lA[c8][j] = ap;
    lB[c8][j] = at;
    __syncthreads();

    float part = 0.f;
    if (tid < 32) {
        float4 ps = make_float4(0.f, 0.f, 0.f, 0.f);
        float4 ts = make_float4(0.f, 0.f, 0.f, 0.f);
#pragma unroll
        for (int k = 0; k < 8; ++k) {
            float4 p = lA[k][tid], w = lB[k][tid];
            ps.x += p.x; ps.y += p.y; ps.z += p.z; ps.w += p.w;
            ts.x += w.x; ts.y += w.y; ts.z += w.z; ts.w += w.w;
        }
        const float pmx = ps.x / flen, pmy = ps.y / flen, pmz = ps.z / flen, pmw = ps.w / flen;
        const float tmx = ts.x / flen, tmy = ts.y / flen, tmz = ts.z / flen, tmw = ts.w / flen;
        float4 iv = img4[(size_t)b * (D_ / 4) + g * 32 + tid];
        part  = sl1f(pmx - tmx) + sl1f(pmy - tmy) + sl1f(pmz - tmz) + sl1f(pmw - tmw);
        part += sl1f(pmx - iv.x * inv_norm) + sl1f(pmy - iv.y * inv_norm)
              + sl1f(pmz - iv.z * inv_norm) + sl1f(pmw - iv.w * inv_norm);
    }
    // reduce 32 lanes of wave 0 (other lanes/waves carry 0)
#pragma unroll
    for (int o = 16; o > 0; o >>= 1) part += __shfl_down(part, o, 64);

    if (tid == 0) {
        float wsum = 0.f;
#pragma unroll
        for (int k = 0; k < NT_ / 8; ++k) {
            int nt = g * (NT_ / 8) + k;
            if (nt < ntmax) wsum += wsSl1[b * NT_ + nt];
        }
        float val = part / (float)D_ + wsum / (flen * (float)D_);
        atomicAdd(out, val * (1.0f / (float)B_));   // device-scope, cross-XCD safe
    }
}

extern "C" void kernel_launch(void* const* d_in, const int* in_sizes, int n_in,
                              void* d_out, int out_size, void* d_ws, size_t ws_size,
                              hipStream_t stream) {
    const float* wtarg = (const float*)d_in[0];   // word_targets [B,T,D]
    const float* img   = (const float*)d_in[1];   // image_targets [B,D]
    const float* preds = (const float*)d_in[2];   // preds [B,T,D]
    const int*   lens  = (const int*)d_in[3];     // decode_lengths [B]
    float* out = (float*)d_out;

    float* wsPred = (float*)d_ws;                          // B*NT*D floats (4 MB)
    float* wsTarg = wsPred + (size_t)B_ * NT_ * D_;        // 4 MB
    float* wsSl1  = wsTarg + (size_t)B_ * NT_ * D_;        // B*NT

    pass1_kernel<<<GRID1_, 256, 0, stream>>>(preds, wtarg, lens, wsPred, wsTarg, wsSl1, out);
    pass2_kernel<<<dim3(8, B_), 256, 0, stream>>>(img, lens, wsPred, wsTarg, wsSl1, out);
}